// Round 1
// baseline (860.333 us; speedup 1.0000x reference)
//
#include <hip/hip_runtime.h>
#include <stdint.h>

#define N_P 100000
#define N_D 50000
#define NE  600000
#define F   128
#define FP  136   // padded LDS/global row for W^T and m tiles (breaks bank conflicts)

typedef __attribute__((ext_vector_type(8))) __bf16 bf16x8;
typedef __attribute__((ext_vector_type(4))) float  f32x4;

static __device__ __forceinline__ float bf2f(uint16_t u){
  union{float f;uint32_t i;} v; v.i = ((uint32_t)u)<<16; return v.f;
}
static __device__ __forceinline__ uint16_t f2bf(float f){
  union{float f;uint32_t i;} v; v.f = f;
  uint32_t i = v.i;
  uint32_t r = i + 0x7fffu + ((i>>16)&1u);   // round-to-nearest-even
  return (uint16_t)(r>>16);
}

// ---------------- degree counting ----------------
__global__ void k_deg(const int* __restrict__ pd_src, const int* __restrict__ pd_dst,
                      const int* __restrict__ dp_src, const int* __restrict__ dp_dst,
                      int* cnt_p_out, int* cnt_d_in, int* cnt_d_out, int* cnt_p_in){
  int i = blockIdx.x*256 + threadIdx.x;
  if (i < NE){
    atomicAdd(&cnt_p_out[pd_src[i]], 1);
    atomicAdd(&cnt_d_in [pd_dst[i]], 1);
    atomicAdd(&cnt_d_out[dp_src[i]], 1);
    atomicAdd(&cnt_p_in [dp_dst[i]], 1);
  }
}

__global__ void k_rs_all(const int* c_po, const int* c_pi, const int* c_do, const int* c_di,
                         float* r_po, float* r_pi, float* r_do, float* r_di){
  int i = blockIdx.x*256 + threadIdx.x;
  if (i < N_P){ r_po[i] = rsqrtf((float)max(c_po[i],1)); r_pi[i] = rsqrtf((float)max(c_pi[i],1)); }
  if (i < N_D){ r_do[i] = rsqrtf((float)max(c_do[i],1)); r_di[i] = rsqrtf((float)max(c_di[i],1)); }
}

// ---------------- hierarchical exclusive scan (two arrays in one pass set) ---
// segment A: cnt over N_D -> off_pd ; segment B: cnt over N_P -> off_dp
__global__ void k_scan1(const int* __restrict__ cA, int nA,
                        const int* __restrict__ cB, int nB,
                        int* __restrict__ bsums, int nbA){
  __shared__ int red[8];
  int b = blockIdx.x, t = threadIdx.x;
  const int* in; int n, bi, slot;
  if (b < nbA){ in = cA; n = nA; bi = b;       slot = bi; }
  else        { in = cB; n = nB; bi = b - nbA; slot = 256 + bi; }
  int i = bi*512 + t;
  int v = (i < n) ? in[i] : 0;
  #pragma unroll
  for (int o = 32; o; o >>= 1) v += __shfl_down(v, o, 64);
  if ((t & 63) == 0) red[t >> 6] = v;
  __syncthreads();
  if (t == 0){ int s = 0; for (int k = 0; k < 8; ++k) s += red[k]; bsums[slot] = s; }
}

__global__ void k_scan2(int* bsums, int nbA, int nbB){
  __shared__ int sh[256];
  int seg = blockIdx.x, t = threadIdx.x;
  int nb = seg ? nbB : nbA;
  int* p = bsums + seg*256;
  int v = (t < nb) ? p[t] : 0;
  sh[t] = v; __syncthreads();
  for (int ofs = 1; ofs < 256; ofs <<= 1){
    int u = (t >= ofs) ? sh[t-ofs] : 0; __syncthreads();
    sh[t] += u; __syncthreads();
  }
  if (t < nb) p[t] = sh[t] - v;   // exclusive
}

__global__ void k_scan3(const int* __restrict__ cA, int nA,
                        const int* __restrict__ cB, int nB,
                        const int* __restrict__ bsums, int nbA,
                        int* __restrict__ offA, int* __restrict__ offB){
  __shared__ int sh[512];
  int b = blockIdx.x, t = threadIdx.x;
  const int* in; int n, bi; int* out; int base;
  if (b < nbA){ in = cA; n = nA; bi = b;       out = offA; base = bsums[bi]; }
  else        { in = cB; n = nB; bi = b - nbA; out = offB; base = bsums[256+bi]; }
  int i = bi*512 + t;
  int v = (i < n) ? in[i] : 0;
  sh[t] = v; __syncthreads();
  for (int ofs = 1; ofs < 512; ofs <<= 1){
    int u = (t >= ofs) ? sh[t-ofs] : 0; __syncthreads();
    sh[t] += u; __syncthreads();
  }
  if (i < n) out[i] = base + sh[t] - v;
  if (b == 0 && t == 0){ offA[nA] = NE; offB[nB] = NE; }
}

// ---------------- CSR fill ----------------
__global__ void k_fill(const int* __restrict__ pd_src, const int* __restrict__ pd_dst,
                       const int* __restrict__ dp_src, const int* __restrict__ dp_dst,
                       const int* __restrict__ off_pd, int* fill_pd, int* __restrict__ col_pd,
                       const int* __restrict__ off_dp, int* fill_dp, int* __restrict__ col_dp){
  int i = blockIdx.x*256 + threadIdx.x;
  if (i < NE){
    int d  = pd_dst[i]; int p  = off_pd[d]  + atomicAdd(&fill_pd[d],  1); col_pd[p]  = pd_src[i];
    int d2 = dp_dst[i]; int p2 = off_dp[d2] + atomicAdd(&fill_dp[d2], 1); col_dp[p2] = dp_src[i];
  }
}

// ---------------- fp32 -> prescaled bf16 feature conversion ----------------
__global__ void k_convert(const float4* __restrict__ hp, const float4* __restrict__ hd,
                          const float* __restrict__ rs_po, const float* __restrict__ rs_do,
                          uint2* __restrict__ P0, uint2* __restrict__ D0){
  int i = blockIdx.x*256 + threadIdx.x;
  const int nP4 = N_P*F/4, nD4 = N_D*F/4;
  if (i < nP4){
    float4 v = hp[i]; float s = rs_po[i >> 5];
    uint2 r;
    r.x = ((uint32_t)f2bf(v.y*s)<<16) | f2bf(v.x*s);
    r.y = ((uint32_t)f2bf(v.w*s)<<16) | f2bf(v.z*s);
    P0[i] = r;
  } else {
    int j = i - nP4;
    if (j < nD4){
      float4 v = hd[j]; float s = rs_do[j >> 5];
      uint2 r;
      r.x = ((uint32_t)f2bf(v.y*s)<<16) | f2bf(v.x*s);
      r.y = ((uint32_t)f2bf(v.w*s)<<16) | f2bf(v.z*s);
      D0[j] = r;
    }
  }
}

// ---------------- W (fp32 KxN row-major) -> bf16 W^T padded [N][FP] ----------
__global__ void k_prepw(const float* w0,const float* w1,const float* w2,
                        const float* w3,const float* w4,const float* w5,
                        uint16_t* __restrict__ wt){
  int m = blockIdx.x;
  const float* W;
  switch(m){ case 0:W=w0;break; case 1:W=w1;break; case 2:W=w2;break;
             case 3:W=w3;break; case 4:W=w4;break; default:W=w5; }
  uint16_t* T = wt + m*F*FP;
  for (int idx = threadIdx.x; idx < F*F; idx += 256){
    int k = idx >> 7, j = idx & 127;
    T[j*FP + k] = f2bf(W[idx]);
  }
}

// ---------------- fused gconv: CSR-gather + (m*rs_in) @ W + b, relu ---------
// OUT_MODE 0: write bf16 intermediate, pre-scaled by rs_next[row]
// OUT_MODE 1: write fp32 final output, no scale
template<int OUT_MODE>
__global__ __launch_bounds__(256, 3) void k_gconv(
    const uint16_t* __restrict__ x,     // [n_src][F] bf16, prescaled by rs_out
    const int* __restrict__ off,        // [n_dst+1]
    const int* __restrict__ col,        // [NE] src indices grouped by dst
    const float* __restrict__ rs_in,    // [n_dst]
    const uint16_t* __restrict__ Wt,    // [F][FP] bf16 transposed W
    const float* __restrict__ bias,     // [F]
    const float* __restrict__ rs_next,  // [n_dst] or null
    void* __restrict__ outp, int n_dst)
{
  __shared__ uint16_t wt_lds[F*FP];    // 34816 B
  __shared__ uint16_t m_lds[64*FP];    // 17408 B
  __shared__ float    b_lds[F];
  const int tid  = threadIdx.x;
  const int lane = tid & 63;
  const int wv   = tid >> 6;

  // stage W^T (bf16, already padded in global) into LDS, 16B chunks
  {
    const uint4* s4 = (const uint4*)Wt;
    uint4* d4 = (uint4*)wt_lds;
    #pragma unroll
    for (int it = 0; it < 9; ++it){
      int idx = it*256 + tid;
      if (idx < (F*FP*2)/16) d4[idx] = s4[idx];
    }
    if (tid < F) b_lds[tid] = bias[tid];
  }

  // ---- aggregation: wave wv owns rows row0..row0+15 ----
  const int row0 = blockIdx.x*64 + wv*16;
  for (int i = 0; i < 16; ++i){
    int r = row0 + i;
    float a0 = 0.f, a1 = 0.f;
    if (r < n_dst){
      int e0 = __builtin_amdgcn_readfirstlane(off[r]);
      int e1 = __builtin_amdgcn_readfirstlane(off[r+1]);
      for (int e = e0; e < e1; e += 4){
        #pragma unroll
        for (int q = 0; q < 4; ++q){
          int ee = e + q;
          bool vld = ee < e1;
          int c = col[vld ? ee : e];
          c = __builtin_amdgcn_readfirstlane(c);
          uint32_t u = *(const uint32_t*)(x + c*F + 2*lane);
          float lo = bf2f((uint16_t)u), hi = bf2f((uint16_t)(u>>16));
          a0 += vld ? lo : 0.f;
          a1 += vld ? hi : 0.f;
        }
      }
      float rs = rs_in[r];
      a0 *= rs; a1 *= rs;
    }
    uint32_t packed = ((uint32_t)f2bf(a1)<<16) | f2bf(a0);
    *(uint32_t*)&m_lds[(wv*16 + i)*FP + 2*lane] = packed;
  }
  __syncthreads();   // covers wt_lds for all waves (m_lds is wave-private)

  // ---- GEMM: 16 rows x 128 cols per wave via mfma_f32_16x16x32_bf16 ----
  f32x4 acc[8];
  #pragma unroll
  for (int t = 0; t < 8; ++t) acc[t] = (f32x4){0.f,0.f,0.f,0.f};
  const int mrow = lane & 15;        // A row / B col within tile
  const int kgrp = lane >> 4;        // k-slice group of 8
  #pragma unroll
  for (int k0 = 0; k0 < F; k0 += 32){
    bf16x8 a = *(const bf16x8*)&m_lds[(wv*16 + mrow)*FP + k0 + kgrp*8];
    #pragma unroll
    for (int t = 0; t < 8; ++t){
      bf16x8 b = *(const bf16x8*)&wt_lds[(t*16 + mrow)*FP + k0 + kgrp*8];
      acc[t] = __builtin_amdgcn_mfma_f32_16x16x32_bf16(a, b, acc[t], 0, 0, 0);
    }
  }

  // ---- epilogue: + bias, relu, (scale for next layer), store ----
  #pragma unroll
  for (int reg = 0; reg < 4; ++reg){
    int rr = row0 + kgrp*4 + reg;    // D row = (lane>>4)*4 + reg  [m89]
    if (rr < n_dst){
      float rsn = (OUT_MODE == 0) ? rs_next[rr] : 0.f;
      #pragma unroll
      for (int t = 0; t < 8; ++t){
        int n = t*16 + mrow;         // D col = lane&15
        float v = acc[t][reg] + b_lds[n];
        v = fmaxf(v, 0.f);
        if (OUT_MODE == 0){
          ((uint16_t*)outp)[rr*F + n] = f2bf(v * rsn);
        } else {
          ((float*)outp)[rr*F + n] = v;
        }
      }
    }
  }
}

extern "C" void kernel_launch(void* const* d_in, const int* in_sizes, int n_in,
                              void* d_out, int out_size, void* d_ws, size_t ws_size,
                              hipStream_t stream) {
  const float* h_p   = (const float*)d_in[0];
  const float* h_d   = (const float*)d_in[1];
  const int* pd_src  = (const int*)d_in[2];
  const int* pd_dst  = (const int*)d_in[3];
  const int* dp_src  = (const int*)d_in[4];
  const int* dp_dst  = (const int*)d_in[5];
  const float* W1_pd = (const float*)d_in[6];   const float* b1_pd = (const float*)d_in[7];
  const float* W1_dp = (const float*)d_in[8];   const float* b1_dp = (const float*)d_in[9];
  const float* W2_pd = (const float*)d_in[10];  const float* b2_pd = (const float*)d_in[11];
  const float* W2_dp = (const float*)d_in[12];  const float* b2_dp = (const float*)d_in[13];
  const float* W3_pd = (const float*)d_in[14];  const float* b3_pd = (const float*)d_in[15];
  const float* W3_dp = (const float*)d_in[16];  const float* b3_dp = (const float*)d_in[17];

  char* w = (char*)d_ws;
  size_t o = 0;
  auto take = [&](size_t bytes)->char*{
    char* p = w + o; o += (bytes + 255) & ~(size_t)255; return p;
  };

  // zeroed int block: cnt_p_out, cnt_p_in, fill_dp (N_P each); cnt_d_out, cnt_d_in, fill_pd (N_D each)
  int* zero_base  = (int*)take((size_t)4*(3*N_P + 3*N_D));
  int* cnt_p_out  = zero_base;
  int* cnt_p_in   = zero_base + N_P;
  int* fill_dp    = zero_base + 2*N_P;
  int* cnt_d_out  = zero_base + 3*N_P;
  int* cnt_d_in   = zero_base + 3*N_P + N_D;
  int* fill_pd    = zero_base + 3*N_P + 2*N_D;
  const size_t zero_bytes = (size_t)4*(3*N_P + 3*N_D);

  int* off_pd   = (int*)take(4*(size_t)(N_D+1));
  int* off_dp   = (int*)take(4*(size_t)(N_P+1));
  int* bsums    = (int*)take(4*512);
  int* col_pd   = (int*)take(4*(size_t)NE);
  int* col_dp   = (int*)take(4*(size_t)NE);
  float* rs_p_out = (float*)take(4*(size_t)N_P);
  float* rs_p_in  = (float*)take(4*(size_t)N_P);
  float* rs_d_out = (float*)take(4*(size_t)N_D);
  float* rs_d_in  = (float*)take(4*(size_t)N_D);
  uint16_t* wt  = (uint16_t*)take(2*(size_t)6*F*FP);
  uint16_t* P0  = (uint16_t*)take(2*(size_t)N_P*F);
  uint16_t* P1  = (uint16_t*)take(2*(size_t)N_P*F);
  uint16_t* P2  = (uint16_t*)take(2*(size_t)N_P*F);
  uint16_t* D0  = (uint16_t*)take(2*(size_t)N_D*F);
  uint16_t* D1  = (uint16_t*)take(2*(size_t)N_D*F);
  uint16_t* D2  = (uint16_t*)take(2*(size_t)N_D*F);

  hipMemsetAsync(zero_base, 0, zero_bytes, stream);

  k_deg<<<(NE+255)/256, 256, 0, stream>>>(pd_src, pd_dst, dp_src, dp_dst,
                                          cnt_p_out, cnt_d_in, cnt_d_out, cnt_p_in);
  k_rs_all<<<(N_P+255)/256, 256, 0, stream>>>(cnt_p_out, cnt_p_in, cnt_d_out, cnt_d_in,
                                              rs_p_out, rs_p_in, rs_d_out, rs_d_in);
  const int nbA = (N_D + 511)/512;   // 98
  const int nbB = (N_P + 511)/512;   // 196
  k_scan1<<<nbA+nbB, 512, 0, stream>>>(cnt_d_in, N_D, cnt_p_in, N_P, bsums, nbA);
  k_scan2<<<2, 256, 0, stream>>>(bsums, nbA, nbB);
  k_scan3<<<nbA+nbB, 512, 0, stream>>>(cnt_d_in, N_D, cnt_p_in, N_P, bsums, nbA, off_pd, off_dp);
  k_fill<<<(NE+255)/256, 256, 0, stream>>>(pd_src, pd_dst, dp_src, dp_dst,
                                           off_pd, fill_pd, col_pd, off_dp, fill_dp, col_dp);
  k_convert<<<((N_P+N_D)*F/4 + 255)/256, 256, 0, stream>>>(
      (const float4*)h_p, (const float4*)h_d, rs_p_out, rs_d_out, (uint2*)P0, (uint2*)D0);
  k_prepw<<<6, 256, 0, stream>>>(W1_pd, W1_dp, W2_pd, W2_dp, W3_pd, W3_dp, wt);

  const int gd = (N_D + 63)/64, gp = (N_P + 63)/64;
  // layer 1
  k_gconv<0><<<gd, 256, 0, stream>>>(P0, off_pd, col_pd, rs_d_in, wt + 0*F*FP, b1_pd, rs_d_out, D1, N_D);
  k_gconv<0><<<gp, 256, 0, stream>>>(D0, off_dp, col_dp, rs_p_in, wt + 1*F*FP, b1_dp, rs_p_out, P1, N_P);
  // layer 2
  k_gconv<0><<<gd, 256, 0, stream>>>(P1, off_pd, col_pd, rs_d_in, wt + 2*F*FP, b2_pd, rs_d_out, D2, N_D);
  k_gconv<0><<<gp, 256, 0, stream>>>(D1, off_dp, col_dp, rs_p_in, wt + 3*F*FP, b2_dp, rs_p_out, P2, N_P);
  // layer 3 (fp32 outputs: h_p3 first, then h_d3)
  k_gconv<1><<<gd, 256, 0, stream>>>(P2, off_pd, col_pd, rs_d_in, wt + 4*F*FP, b3_pd, nullptr,
                                     (float*)d_out + (size_t)N_P*F, N_D);
  k_gconv<1><<<gp, 256, 0, stream>>>(D2, off_dp, col_dp, rs_p_in, wt + 5*F*FP, b3_dp, nullptr,
                                     (float*)d_out, N_P);
}